// Round 1
// baseline (1021.833 us; speedup 1.0000x reference)
//
#include <hip/hip_runtime.h>
#include <hip/hip_bf16.h>

typedef __attribute__((ext_vector_type(4))) float f32x4;
typedef __attribute__((ext_vector_type(8))) short short8;
typedef __attribute__((ext_vector_type(4))) unsigned int u32x4;

#define F_IN 45056
#define M_ROWS 4096
#define N_OUT 256
#define KCHUNK 5632
#define KSTEPS 88
#define ROWSTRIDE32 (32 * F_IN)

// ws layout (bytes):
//   w1p  (bf16 packed, swizzled): 8*88*2048*16 = 23,068,672
//   part (fp32 [8][4096][256])  : 33,554,432
//   w2t  (fp32 [512][32])       : 65,536
//   w3t  (fp32 [32][32])        : 4,096
#define WS_PART 23068672UL
#define WS_W2T (WS_PART + 33554432UL)
#define WS_W3T (WS_W2T + 65536UL)

__device__ __forceinline__ unsigned cvt2(float a, float b) {
  __hip_bfloat162 h = __float22bfloat162_rn(make_float2(a, b));
  unsigned u;
  __builtin_memcpy(&u, &h, 4);
  return u;
}

// ---------------- kernel 0: pack W1 -> bf16 swizzled chunks; transpose W2/W3
__global__ __launch_bounds__(256) void nnue_pack(
    const float* __restrict__ w1, const float* __restrict__ w2,
    const float* __restrict__ w3, unsigned short* __restrict__ w1p,
    float* __restrict__ w2t, float* __restrict__ w3t) {
  int id = blockIdx.x * 256 + threadIdx.x;
  if (id < 1441792) {
    // chunk id: [s*88+kt][q], q = n*8 + kc_phys, logical kc = kc_phys ^ (n&7)
    int q = id & 2047;
    int n = q >> 3;
    int kcp = q & 7;
    int kc = kcp ^ (n & 7);
    int k = (id >> 11) * 64 + kc * 8;  // (s*88+kt)*64 + kc*8
    const float* src = w1 + (long)n * F_IN + k;
    float4 v0 = *(const float4*)(src);
    float4 v1 = *(const float4*)(src + 4);
    u32x4 u;
    u.x = cvt2(v0.x, v0.y);
    u.y = cvt2(v0.z, v0.w);
    u.z = cvt2(v1.x, v1.y);
    u.w = cvt2(v1.z, v1.w);
    *(u32x4*)(w1p + (long)id * 8) = u;
  } else if (id < 1441792 + 16384) {
    int e = id - 1441792;
    int j = e >> 5, o = e & 31;
    w2t[e] = w2[o * 512 + j];  // w2t[j*32+o]
  } else {
    int e = id - (1441792 + 16384);
    int i = e >> 5, o = e & 31;
    w3t[e] = w3[o * 32 + i];  // w3t[i*32+o]
  }
}

// ---------------- kernel 1: layer-1 GEMM, K-split partials
// grid 256 = 32 Mtiles x 8 K-chunks (s = blockIdx&7 -> XCD-pinned W1 slice)
__global__ __launch_bounds__(512) void nnue_l1(
    const float* __restrict__ x, const unsigned short* __restrict__ w1p,
    float* __restrict__ part) {
  extern __shared__ unsigned char smem[];  // 98304: As[2]@{0,16384}, Bs[2]@{32768,65536}
  const int tid = threadIdx.x;
  const int wave = tid >> 6;
  const int lane = tid & 63;
  const int s = blockIdx.x & 7;
  const int mt = blockIdx.x >> 3;
  const int Mbase = mt * 128;

  const int wm = wave >> 2;  // 0..1
  const int wn = wave & 3;   // 0..3
  const int fl = lane & 15;
  const int fq = lane >> 4;

  // A staging coords: per pass p, row m = a_m0 + 32p, k = a_kq*4
  const int a_m0 = tid >> 4;  // 0..31
  const int a_kq = tid & 15;
  const int a_kc = a_kq >> 1;
  const int a_half = a_kq & 1;

  const float* aptr =
      x + (long)(Mbase + a_m0) * F_IN + (long)s * KCHUNK + a_kq * 4;

  int awoff[4];
#pragma unroll
  for (int p = 0; p < 4; ++p) {
    int m = a_m0 + p * 32;
    int pi = m * 8 + (a_kc ^ (m & 7));  // XOR-swizzled chunk index
    awoff[p] = pi * 16 + a_half * 8;
  }

  const unsigned short* bsrc0 =
      w1p + ((long)(s * KSTEPS) * 2048 + wave * 64 + lane) * 8;

  f32x4 acc[4][4];
#pragma unroll
  for (int i = 0; i < 4; ++i)
#pragma unroll
    for (int j = 0; j < 4; ++j) acc[i][j] = f32x4{0.f, 0.f, 0.f, 0.f};

  // prologue: issue A loads + B glds for kt=0 (buf 0)
  float4 areg[4];
#pragma unroll
  for (int p = 0; p < 4; ++p)
    areg[p] = *(const float4*)(aptr + (long)p * ROWSTRIDE32);
  {
    unsigned char* ldsb = smem + 32768 + wave * 1024;
#pragma unroll
    for (int j = 0; j < 4; ++j) {
      __builtin_amdgcn_global_load_lds(
          (const __attribute__((address_space(1))) unsigned int*)(bsrc0 +
                                                                  j * 512 * 8),
          (__attribute__((address_space(3))) unsigned int*)(ldsb + j * 8192),
          16, 0, 0);
    }
  }

  for (int kt = 0; kt < KSTEPS; ++kt) {
    const int buf = kt & 1;
    unsigned char* As = smem + buf * 16384;
    // commit A tile kt (loads issued last iter; cvt+ds_write now)
#pragma unroll
    for (int p = 0; p < 4; ++p) {
      unsigned lo = cvt2(areg[p].x, areg[p].y);
      unsigned hi = cvt2(areg[p].z, areg[p].w);
      unsigned* dst = (unsigned*)(As + awoff[p]);
      dst[0] = lo;
      dst[1] = hi;
    }
    __syncthreads();  // drains our ds_writes + B glds for this buf

    if (kt + 1 < KSTEPS) {  // prefetch kt+1 into other buffer (async over compute)
      const float* ap = aptr + (kt + 1) * 64;
#pragma unroll
      for (int p = 0; p < 4; ++p)
        areg[p] = *(const float4*)(ap + (long)p * ROWSTRIDE32);
      const unsigned short* gb = bsrc0 + (long)(kt + 1) * 2048 * 8;
      unsigned char* ldsb = smem + 32768 + (buf ^ 1) * 32768 + wave * 1024;
#pragma unroll
      for (int j = 0; j < 4; ++j) {
        __builtin_amdgcn_global_load_lds(
            (const __attribute__((address_space(1))) unsigned int*)(gb +
                                                                    j * 512 * 8),
            (__attribute__((address_space(3))) unsigned int*)(ldsb + j * 8192),
            16, 0, 0);
      }
    }

    const unsigned char* Ab = smem + buf * 16384;
    const unsigned char* Bb = smem + 32768 + buf * 32768;
#pragma unroll
    for (int kk = 0; kk < 2; ++kk) {
      short8 af[4], bfr[4];
#pragma unroll
      for (int mi = 0; mi < 4; ++mi) {
        int m = wm * 64 + mi * 16 + fl;
        int pi = m * 8 + ((kk * 4 + fq) ^ (m & 7));
        af[mi] = *(const short8*)(Ab + pi * 16);
      }
#pragma unroll
      for (int ni = 0; ni < 4; ++ni) {
        int n = wn * 64 + ni * 16 + fl;
        int pi = n * 8 + ((kk * 4 + fq) ^ (n & 7));
        bfr[ni] = *(const short8*)(Bb + pi * 16);
      }
#pragma unroll
      for (int mi = 0; mi < 4; ++mi)
#pragma unroll
        for (int ni = 0; ni < 4; ++ni)
          acc[mi][ni] = __builtin_amdgcn_mfma_f32_16x16x32_bf16(
              af[mi], bfr[ni], acc[mi][ni], 0, 0, 0);
    }
  }

  // epilogue: C/D layout col=lane&15, row=(lane>>4)*4+reg
  float* pout = part + ((long)s * M_ROWS + Mbase) * N_OUT;
#pragma unroll
  for (int mi = 0; mi < 4; ++mi)
#pragma unroll
    for (int ni = 0; ni < 4; ++ni) {
      int n = wn * 64 + ni * 16 + fl;
#pragma unroll
      for (int r = 0; r < 4; ++r) {
        int m = wm * 64 + mi * 16 + fq * 4 + r;
        pout[(long)m * N_OUT + n] = acc[mi][ni][r];
      }
    }
}

// ---------------- kernel 2: reduce partials + bias/relu + tail MLP + sigmoid
__global__ __launch_bounds__(256) void nnue_tail(
    const float* __restrict__ part, const float* __restrict__ b1,
    const float* __restrict__ w2t, const float* __restrict__ b2,
    const float* __restrict__ w3t, const float* __restrict__ b3,
    const float* __restrict__ w4, const float* __restrict__ b4,
    float* __restrict__ out) {
  __shared__ float a_lds[2048];  // 4 rows x 512
  const int tid = threadIdx.x;
  const int b0 = blockIdx.x * 4;
  // phase 1: a[r][j] = relu(b1 + sum_s P[s][m][o])
#pragma unroll
  for (int i = 0; i < 8; ++i) {
    int idx = i * 256 + tid;
    int r = idx >> 9;
    int j = idx & 511;
    int o = j & 255;
    int m = (b0 + r) * 2 + (j >> 8);
    const float* p = part + (long)m * N_OUT + o;
    float sum = b1[o];
#pragma unroll
    for (int s2 = 0; s2 < 8; ++s2) sum += p[(long)s2 * M_ROWS * N_OUT];
    a_lds[idx] = fmaxf(sum, 0.f);
  }
  __syncthreads();
  // phase 2: one wave per row; lane: o = ln&31, half = ln>>5
  const int wv = tid >> 6, ln = tid & 63;
  const int o = ln & 31, half = ln >> 5;
  const float* arow = a_lds + wv * 512 + half * 256;
  const float* wcol = w2t + half * 256 * 32 + o;  // w2t[j*32+o]
  float acc = 0.f;
#pragma unroll 8
  for (int jj = 0; jj < 256; ++jj) acc = fmaf(arow[jj], wcol[jj * 32], acc);
  acc += __shfl_xor(acc, 32);
  float h2 = fmaxf(acc + b2[o], 0.f);  // all 64 lanes: lane l holds h2[l&31]
  // phase 3
  float h3 = b3[o];
#pragma unroll
  for (int i = 0; i < 32; ++i) {
    float hv = __shfl(h2, i, 64);
    h3 = fmaf(hv, w3t[i * 32 + o], h3);
  }
  h3 = fmaxf(h3, 0.f);
  float v = h3 * w4[o];
  v += __shfl_xor(v, 16);
  v += __shfl_xor(v, 8);
  v += __shfl_xor(v, 4);
  v += __shfl_xor(v, 2);
  v += __shfl_xor(v, 1);
  if (ln == 0) {
    float z = v + b4[0];
    out[b0 + wv] = 1.f / (1.f + expf(-z));
  }
}

extern "C" void kernel_launch(void* const* d_in, const int* in_sizes, int n_in,
                              void* d_out, int out_size, void* d_ws,
                              size_t ws_size, hipStream_t stream) {
  const float* x = (const float*)d_in[0];
  const float* W1 = (const float*)d_in[1];
  const float* b1 = (const float*)d_in[2];
  const float* W2 = (const float*)d_in[3];
  const float* b2 = (const float*)d_in[4];
  const float* W3 = (const float*)d_in[5];
  const float* b3 = (const float*)d_in[6];
  const float* W4 = (const float*)d_in[7];
  const float* b4 = (const float*)d_in[8];
  float* out = (float*)d_out;

  unsigned short* w1p = (unsigned short*)d_ws;
  float* part = (float*)((char*)d_ws + WS_PART);
  float* w2t = (float*)((char*)d_ws + WS_W2T);
  float* w3t = (float*)((char*)d_ws + WS_W3T);

  nnue_pack<<<5700, 256, 0, stream>>>(W1, W2, W3, w1p, w2t, w3t);
  nnue_l1<<<256, 512, 98304, stream>>>(x, w1p, part);
  nnue_tail<<<512, 256, 0, stream>>>(part, b1, w2t, b2, w3t, b3, W4, b4, out);
}